// Round 1
// baseline (2841.463 us; speedup 1.0000x reference)
//
#include <hip/hip_runtime.h>

// ---------------------------------------------------------------------------
// GIN dual-branch forward for MI355X. Round 1: correct fp32 implementation.
//   branch: h=relu((x+scatter(x))@W1+b1); h2=relu((h+scatter(h))@W2+b2)
//           p=[max|mean]-pool(h2, sorted batch); MLP heads.
// Key choice: GIN-layer-2 GEMM is fused with pooling per graph (batch sorted,
// nodes contiguous per graph) so the [50000 x 930] intermediate is never
// materialized (saves 372 MB of HBM traffic + keeps ws < 45 MB).
// ---------------------------------------------------------------------------

static constexpr int NG = 256;  // number of graphs

// ---- segment bookkeeping ---------------------------------------------------
__global__ void hist_kernel(const int* __restrict__ seg, int N, int* __restrict__ cnt) {
    int i = blockIdx.x * blockDim.x + threadIdx.x;
    if (i < N) atomicAdd(&cnt[seg[i]], 1);
}

__global__ void scan_kernel(const int* __restrict__ cnt, int* __restrict__ offs) {
    if (threadIdx.x == 0) {
        int acc = 0;
        for (int g = 0; g < NG; ++g) { offs[g] = acc; acc += cnt[g]; }
        offs[NG] = acc;
    }
}

// ---- edge scatter-add: agg[dst] += x[src] ---------------------------------
// one wave per edge; lanes stride the feature dim. 4 edges / 256-thread block.
template<int F>
__global__ void scatter_kernel(const float* __restrict__ x, const int* __restrict__ ei,
                               int E, float* __restrict__ agg) {
    int gt = blockIdx.x * blockDim.x + threadIdx.x;
    int e = gt >> 6;
    int lane = gt & 63;
    if (e >= E) return;
    int src = ei[e];        // edge_index[0][e]
    int dst = ei[E + e];    // edge_index[1][e]
    const float* xs = x + (size_t)src * F;
    float* ad = agg + (size_t)dst * F;
    #pragma unroll
    for (int k = lane; k < F; k += 64) atomicAdd(&ad[k], xs[k]);
}

// ---- GIN layer 1: out = relu((x+agg) @ W + b), F -> F ---------------------
// TILE nodes staged transposed in LDS; thread j owns output col j.
template<int F, int BD, int TILE>
__global__ __launch_bounds__(BD) void gin_linear_kernel(
        const float* __restrict__ x, const float* __restrict__ agg,
        const float* __restrict__ W, const float* __restrict__ b,
        float* __restrict__ out, int N) {
    __shared__ __align__(16) float Vt[F][TILE];
    int node0 = blockIdx.x * TILE;
    if (node0 >= N) return;
    int nvalid = N - node0; if (nvalid > TILE) nvalid = TILE;
    for (int idx = threadIdx.x; idx < F * TILE; idx += BD) {
        int n = idx / F, k = idx % F;
        float v = 0.f;
        if (n < nvalid) {
            size_t o = (size_t)(node0 + n) * F + k;
            v = x[o] + agg[o];
        }
        Vt[k][n] = v;
    }
    __syncthreads();
    int j = threadIdx.x;
    if (j < F) {
        float acc[TILE];
        #pragma unroll
        for (int n = 0; n < TILE; ++n) acc[n] = 0.f;
        for (int k = 0; k < F; ++k) {
            float w = W[k * F + j];
            const float4* row = (const float4*)&Vt[k][0];
            #pragma unroll
            for (int q = 0; q < TILE / 4; ++q) {
                float4 a = row[q];
                acc[q * 4 + 0] += a.x * w;
                acc[q * 4 + 1] += a.y * w;
                acc[q * 4 + 2] += a.z * w;
                acc[q * 4 + 3] += a.w * w;
            }
        }
        float bj = b[j];
        for (int n = 0; n < nvalid; ++n)
            out[(size_t)(node0 + n) * F + j] = fmaxf(acc[n] + bj, 0.f);
    }
}

// ---- fused GIN layer 2 + max/mean pool ------------------------------------
// one block per graph (batch sorted -> contiguous node range [offs[g],offs[g+1])).
// h2 rows are computed tile-by-tile and pooled in registers; h2 never hits HBM.
// p layout per graph: [max(F_OUT) | mean(F_OUT)].
template<int F_IN, int F_OUT, int COLS, int TILE>
__global__ __launch_bounds__(256) void gin_pool_kernel(
        const float* __restrict__ h, const float* __restrict__ agg,
        const float* __restrict__ W, const float* __restrict__ b,
        const int* __restrict__ offs, float* __restrict__ p) {
    __shared__ __align__(16) float Vt[F_IN][TILE];
    int g = blockIdx.x;
    int s = offs[g], e = offs[g + 1];
    int tid = threadIdx.x;
    float mx[COLS], sm[COLS], bv[COLS];
    #pragma unroll
    for (int c = 0; c < COLS; ++c) {
        int col = tid + c * 256;
        mx[c] = 0.f; sm[c] = 0.f;
        bv[c] = (col < F_OUT) ? b[col] : 0.f;
    }
    for (int n0 = s; n0 < e; n0 += TILE) {
        int nvalid = e - n0; if (nvalid > TILE) nvalid = TILE;
        __syncthreads();
        for (int idx = tid; idx < F_IN * TILE; idx += 256) {
            int n = idx / F_IN, k = idx % F_IN;
            float v = 0.f;
            if (n < nvalid) {
                size_t o = (size_t)(n0 + n) * F_IN + k;
                v = h[o] + agg[o];
            }
            Vt[k][n] = v;
        }
        __syncthreads();
        float acc[TILE][COLS];
        #pragma unroll
        for (int n = 0; n < TILE; ++n)
            #pragma unroll
            for (int c = 0; c < COLS; ++c) acc[n][c] = 0.f;
        for (int k = 0; k < F_IN; ++k) {
            float w[COLS];
            #pragma unroll
            for (int c = 0; c < COLS; ++c) {
                int col = tid + c * 256;
                w[c] = (col < F_OUT) ? W[(size_t)k * F_OUT + col] : 0.f;
            }
            const float4* row = (const float4*)&Vt[k][0];
            #pragma unroll
            for (int q = 0; q < TILE / 4; ++q) {
                float4 a = row[q];
                #pragma unroll
                for (int c = 0; c < COLS; ++c) {
                    acc[q * 4 + 0][c] += a.x * w[c];
                    acc[q * 4 + 1][c] += a.y * w[c];
                    acc[q * 4 + 2][c] += a.z * w[c];
                    acc[q * 4 + 3][c] += a.w * w[c];
                }
            }
        }
        for (int n = 0; n < nvalid; ++n) {
            #pragma unroll
            for (int c = 0; c < COLS; ++c) {
                float v = fmaxf(acc[n][c] + bv[c], 0.f);
                mx[c] = fmaxf(mx[c], v);
                sm[c] += v;
            }
        }
    }
    int ng = e - s;
    float den = (float)(ng > 0 ? ng : 1);
    #pragma unroll
    for (int c = 0; c < COLS; ++c) {
        int col = tid + c * 256;
        if (col < F_OUT) {
            p[(size_t)g * (2 * F_OUT) + col] = mx[c];
            p[(size_t)g * (2 * F_OUT) + F_OUT + col] = sm[c] / den;
        }
    }
}

// ---- dense FC: C[M,N] = (relu?)(A[M,K] @ W[K,N] + b) ----------------------
// 32 rows x 256 cols per block; A chunk transposed in LDS (pad 36 for b128).
template<bool RELU>
__global__ __launch_bounds__(256) void fc_kernel(
        const float* __restrict__ A, const float* __restrict__ W,
        const float* __restrict__ b, float* __restrict__ C,
        int M, int K, int N) {
    constexpr int KT = 128;
    __shared__ __align__(16) float At[KT][36];
    int colBlocks = N >> 8;
    int cb = blockIdx.x % colBlocks;
    int rb = blockIdx.x / colBlocks;
    int row0 = rb * 32;
    int col = cb * 256 + threadIdx.x;
    float acc[32];
    #pragma unroll
    for (int r = 0; r < 32; ++r) acc[r] = 0.f;
    for (int k0 = 0; k0 < K; k0 += KT) {
        int kt = K - k0; if (kt > KT) kt = KT;
        __syncthreads();
        for (int r = 0; r < 32; ++r)
            for (int kl = threadIdx.x; kl < kt; kl += 256)
                At[kl][r] = A[(size_t)(row0 + r) * K + k0 + kl];
        __syncthreads();
        for (int kl = 0; kl < kt; ++kl) {
            float w = W[(size_t)(k0 + kl) * N + col];
            #pragma unroll
            for (int q = 0; q < 8; ++q) {
                float4 a = *(const float4*)&At[kl][q * 4];
                acc[q * 4 + 0] += a.x * w;
                acc[q * 4 + 1] += a.y * w;
                acc[q * 4 + 2] += a.z * w;
                acc[q * 4 + 3] += a.w * w;
            }
        }
    }
    float bb = b[col];
    #pragma unroll
    for (int r = 0; r < 32; ++r) {
        float v = acc[r] + bb;
        if (RELU) v = fmaxf(v, 0.f);
        C[(size_t)(row0 + r) * N + col] = v;
    }
}

// ---- final head: z[row] = dot(A[row,:], w) + b[0], K == 256 ----------------
__global__ __launch_bounds__(256) void final_dot_kernel(
        const float* __restrict__ A, const float* __restrict__ w,
        const float* __restrict__ b, float* __restrict__ z, int K) {
    int row = blockIdx.x;
    int tid = threadIdx.x;
    float v = (tid < K) ? A[(size_t)row * K + tid] * w[tid] : 0.f;
    #pragma unroll
    for (int o = 32; o > 0; o >>= 1) v += __shfl_down(v, o, 64);
    __shared__ float red[4];
    if ((tid & 63) == 0) red[tid >> 6] = v;
    __syncthreads();
    if (tid == 0) z[row] = red[0] + red[1] + red[2] + red[3] + b[0];
}

// ---------------------------------------------------------------------------
static inline int cdiv(int a, int b) { return (a + b - 1) / b; }

template<int F, int FO, int COLS, int BD>
static void run_branch(const float* feat, const int* ei, int E, int N,
                       const int* seg,
                       const float* W1, const float* b1,
                       const float* W2, const float* b2,
                       const float* fw1, const float* fb1,
                       const float* fw2, const float* fb2,
                       const float* hw1, const float* hb1,
                       const float* hw2, const float* hb2,
                       float* agg, float* h1, float* p, float* t1, float* t2,
                       int* cnt, int* offs,
                       float* xg_out, float* z_out, hipStream_t stream) {
    hipMemsetAsync(cnt, 0, NG * sizeof(int), stream);
    hist_kernel<<<cdiv(N, 256), 256, 0, stream>>>(seg, N, cnt);
    scan_kernel<<<1, 64, 0, stream>>>(cnt, offs);

    // GIN layer 1
    hipMemsetAsync(agg, 0, (size_t)N * F * sizeof(float), stream);
    scatter_kernel<F><<<cdiv(E, 4), 256, 0, stream>>>(feat, ei, E, agg);
    gin_linear_kernel<F, BD, 8><<<cdiv(N, 8), BD, 0, stream>>>(feat, agg, W1, b1, h1, N);

    // GIN layer 2 fused with pooling
    hipMemsetAsync(agg, 0, (size_t)N * F * sizeof(float), stream);
    scatter_kernel<F><<<cdiv(E, 4), 256, 0, stream>>>(h1, ei, E, agg);
    gin_pool_kernel<F, FO, COLS, 8><<<NG, 256, 0, stream>>>(h1, agg, W2, b2, offs, p);

    // FC heads
    const int Kfc = 2 * FO;
    fc_kernel<true ><<<(1024 >> 8) * (NG / 32), 256, 0, stream>>>(p,  fw1, fb1, t1, NG, Kfc,  1024);
    fc_kernel<false><<<( 512 >> 8) * (NG / 32), 256, 0, stream>>>(t1, fw2, fb2, xg_out, NG, 1024, 512);
    fc_kernel<true ><<<( 256 >> 8) * (NG / 32), 256, 0, stream>>>(xg_out, hw1, hb1, t2, NG, 512, 256);
    final_dot_kernel<<<NG, 256, 0, stream>>>(t2, hw2, hb2, z_out, 256);
}

extern "C" void kernel_launch(void* const* d_in, const int* in_sizes, int n_in,
                              void* d_out, int out_size, void* d_ws, size_t ws_size,
                              hipStream_t stream) {
    (void)n_in; (void)out_size; (void)ws_size;
    const float* x      = (const float*)d_in[1];
    const int*   ei     = (const int*)  d_in[2];
    const int*   batch  = (const int*)  d_in[3];
    const float* a      = (const float*)d_in[4];
    const int*   ed     = (const int*)  d_in[5];
    const int*   c      = (const int*)  d_in[6];
    const float* W1  = (const float*)d_in[7],  *b1  = (const float*)d_in[8];
    const float* W2  = (const float*)d_in[9],  *b2  = (const float*)d_in[10];
    const float* W3  = (const float*)d_in[11], *b3  = (const float*)d_in[12];
    const float* W4  = (const float*)d_in[13], *b4  = (const float*)d_in[14];
    const float* fg_w1  = (const float*)d_in[15], *fg_b1  = (const float*)d_in[16];
    const float* fg_w2  = (const float*)d_in[17], *fg_b2  = (const float*)d_in[18];
    const float* fg1_w1 = (const float*)d_in[19], *fg1_b1 = (const float*)d_in[20];
    const float* fg1_w2 = (const float*)d_in[21], *fg1_b2 = (const float*)d_in[22];
    const float* ff_w1  = (const float*)d_in[23], *ff_b1  = (const float*)d_in[24];
    const float* ff_w2  = (const float*)d_in[25], *ff_b2  = (const float*)d_in[26];
    const float* ff1_w1 = (const float*)d_in[27], *ff1_b1 = (const float*)d_in[28];
    const float* ff1_w2 = (const float*)d_in[29], *ff1_b2 = (const float*)d_in[30];

    const int N1 = in_sizes[1] / 93;
    const int E1 = in_sizes[2] / 2;
    const int N2 = in_sizes[4] / 43;
    const int E2 = in_sizes[5] / 2;

    float* out = (float*)d_out;
    float* z   = out;                       // [256]
    float* xg  = out + 256;                 // [256,512]
    float* xg1 = out + 256 + 256 * 512;     // [256,512]
    float* z1  = out + 256 + 2 * 256 * 512; // [256]

    // workspace carve-out (~41 MB total)
    char* wsb = (char*)d_ws;
    size_t off = 0;
    auto carve = [&](size_t bytes) {
        void* ptr = wsb + off;
        off = (off + bytes + 255) & ~(size_t)255;
        return ptr;
    };
    float* agg = (float*)carve((size_t)N1 * 93 * sizeof(float));  // reused by branch 2
    float* h1  = (float*)carve((size_t)N1 * 93 * sizeof(float));
    float* p   = (float*)carve((size_t)NG * 1860 * sizeof(float));
    float* t1  = (float*)carve((size_t)NG * 1024 * sizeof(float));
    float* t2  = (float*)carve((size_t)NG * 256 * sizeof(float));
    int*   cnt  = (int*)carve(NG * sizeof(int));
    int*   offs = (int*)carve((NG + 1) * sizeof(int));

    // branch 1: 93 -> 93 -> 930, pool 1860
    run_branch<93, 930, 4, 128>(x, ei, E1, N1, batch,
                                W1, b1, W2, b2,
                                fg_w1, fg_b1, fg_w2, fg_b2,
                                ff_w1, ff_b1, ff_w2, ff_b2,
                                agg, h1, p, t1, t2, cnt, offs,
                                xg, z, stream);

    // branch 2: 43 -> 43 -> 430, pool 860 (reuses all scratch)
    run_branch<43, 430, 2, 64>(a, ed, E2, N2, c,
                               W3, b3, W4, b4,
                               fg1_w1, fg1_b1, fg1_w2, fg1_b2,
                               ff1_w1, ff1_b1, ff1_w2, ff1_b2,
                               agg, h1, p, t1, t2, cnt, offs,
                               xg1, z1, stream);
}

// Round 2
// 2775.776 us; speedup vs baseline: 1.0237x; 1.0237x over previous
//
#include <hip/hip_runtime.h>

// ---------------------------------------------------------------------------
// Round 2: CSR gather (no float atomics) + column-parallel fused GIN2+pool
// with conflict-free LDS broadcast reads, + retiled FC stack.
// ---------------------------------------------------------------------------

static constexpr int NG = 256;  // number of graphs

// ---- segment bookkeeping ---------------------------------------------------
__global__ void hist_kernel(const int* __restrict__ seg, int N, int* __restrict__ cnt) {
    int i = blockIdx.x * blockDim.x + threadIdx.x;
    if (i < N) atomicAdd(&cnt[seg[i]], 1);
}

__global__ void seg_scan_kernel(const int* __restrict__ cnt, int* __restrict__ offs) {
    if (threadIdx.x == 0) {
        int acc = 0;
        for (int g = 0; g < NG; ++g) { offs[g] = acc; acc += cnt[g]; }
        offs[NG] = acc;
    }
}

// ---- CSR build: histogram dst -> prefix scan -> fill ----------------------
__global__ void deg_kernel(const int* __restrict__ ei, int E, int* __restrict__ deg) {
    int e = blockIdx.x * blockDim.x + threadIdx.x;
    if (e < E) atomicAdd(&deg[ei[E + e]], 1);   // dst = ei[E+e]
}

// block scans a 1024-elem chunk (4 per thread + LDS Hillis-Steele over 256)
__global__ __launch_bounds__(256) void scan1_kernel(const int* __restrict__ deg, int N,
                                                    int* __restrict__ excl,
                                                    int* __restrict__ bsum) {
    __shared__ int sh[256];
    int base = blockIdx.x * 1024;
    int t = threadIdx.x;
    int v[4];
    int s = 0;
    #pragma unroll
    for (int i = 0; i < 4; ++i) {
        int idx = base + t * 4 + i;
        v[i] = s;                             // exclusive within thread
        s += (idx < N) ? deg[idx] : 0;
    }
    sh[t] = s;
    __syncthreads();
    for (int off = 1; off < 256; off <<= 1) {
        int xv = (t >= off) ? sh[t - off] : 0;
        __syncthreads();
        sh[t] += xv;
        __syncthreads();
    }
    int texcl = (t > 0) ? sh[t - 1] : 0;
    #pragma unroll
    for (int i = 0; i < 4; ++i) {
        int idx = base + t * 4 + i;
        if (idx < N) excl[idx] = texcl + v[i];
    }
    if (t == 255) bsum[blockIdx.x] = sh[255];
}

__global__ void scan2_kernel(int* __restrict__ bsum, int nb) {
    if (threadIdx.x == 0) {
        int acc = 0;
        for (int i = 0; i < nb; ++i) { int t = bsum[i]; bsum[i] = acc; acc += t; }
    }
}

__global__ void scan3_kernel(int* __restrict__ excl, const int* __restrict__ bsum,
                             int N, int E) {
    int i = blockIdx.x * blockDim.x + threadIdx.x;
    if (i < N) excl[i] += bsum[i >> 10];
    if (i == 0) excl[N] = E;
}

__global__ void copy_kernel(int* __restrict__ dst, const int* __restrict__ src, int N) {
    int i = blockIdx.x * blockDim.x + threadIdx.x;
    if (i < N) dst[i] = src[i];
}

__global__ void fill_csr_kernel(const int* __restrict__ ei, int E,
                                int* __restrict__ cursor, int* __restrict__ csr) {
    int e = blockIdx.x * blockDim.x + threadIdx.x;
    if (e < E) {
        int dst = ei[E + e];
        int pos = atomicAdd(&cursor[dst], 1);
        csr[pos] = ei[e];                    // src
    }
}

// ---- gather: agg[n] = sum_{e: dst==n} x[src_e]  (wave per node) -----------
template<int F>
__global__ __launch_bounds__(256) void gather_kernel(const float* __restrict__ x,
        const int* __restrict__ csr, const int* __restrict__ ro,
        float* __restrict__ agg, int N) {
    int wave = (blockIdx.x * 256 + threadIdx.x) >> 6;
    int lane = threadIdx.x & 63;
    if (wave >= N) return;
    int s = ro[wave], e = ro[wave + 1];
    float a0 = 0.f, a1 = 0.f;
    const bool l0 = lane < F;
    const bool l1 = (lane + 64) < F;
    for (int i = s; i < e; ++i) {
        const float* row = x + (size_t)csr[i] * F;
        if (l0) a0 += row[lane];
        if (l1) a1 += row[lane + 64];
    }
    float* o = agg + (size_t)wave * F;
    if (l0) o[lane] = a0;
    if (l1) o[lane + 64] = a1;
}

// ---- GIN layer 1: out = relu((x+agg) @ W + b), F -> F ---------------------
// 32-node tile, padded LDS Vt[F][36] (16B-aligned rows, broadcast b128 reads)
template<int F, int BD>
__global__ __launch_bounds__(BD) void gin_linear_kernel(
        const float* __restrict__ x, const float* __restrict__ agg,
        const float* __restrict__ W, const float* __restrict__ b,
        float* __restrict__ out, int N) {
    constexpr int TILE = 32, PAD = 36;
    __shared__ __align__(16) float Vt[F][PAD];
    int node0 = blockIdx.x * TILE;
    if (node0 >= N) return;
    int nvalid = N - node0; if (nvalid > TILE) nvalid = TILE;
    if (nvalid < TILE) {
        for (int idx = threadIdx.x; idx < F * TILE; idx += BD)
            Vt[idx % F][idx / F] = 0.f;
        __syncthreads();
    }
    int total = nvalid * F;
    const float* xs = x + (size_t)node0 * F;
    const float* as = agg + (size_t)node0 * F;
    for (int f = threadIdx.x; f < total; f += BD)
        Vt[f % F][f / F] = xs[f] + as[f];
    __syncthreads();
    int j = threadIdx.x;
    if (j < F) {
        float acc[TILE];
        #pragma unroll
        for (int n = 0; n < TILE; ++n) acc[n] = 0.f;
        for (int k = 0; k < F; ++k) {
            float w = W[k * F + j];
            const float4* row = (const float4*)&Vt[k][0];
            #pragma unroll
            for (int q = 0; q < TILE / 4; ++q) {
                float4 a = row[q];
                acc[q * 4 + 0] += a.x * w;
                acc[q * 4 + 1] += a.y * w;
                acc[q * 4 + 2] += a.z * w;
                acc[q * 4 + 3] += a.w * w;
            }
        }
        float bj = b[j];
        for (int n = 0; n < nvalid; ++n)
            out[(size_t)(node0 + n) * F + j] = fmaxf(acc[n] + bj, 0.f);
    }
}

// ---- fused GIN layer 2 + max/mean pool ------------------------------------
// grid = NG * CB; block (g, cb) handles cols [cb*512, cb*512+512), 2 cols/thread.
// All lanes read the same Vt address -> LDS broadcast, conflict-free.
template<int F_IN, int F_OUT, int CB>
__global__ __launch_bounds__(256) void gin_pool_kernel(
        const float* __restrict__ h, const float* __restrict__ agg,
        const float* __restrict__ W, const float* __restrict__ b,
        const int* __restrict__ offs, float* __restrict__ p) {
    constexpr int TILE = 32, PAD = 36;
    __shared__ __align__(16) float Vt[F_IN][PAD];
    int g  = blockIdx.x / CB;
    int cb = blockIdx.x % CB;
    int tid = threadIdx.x;
    int c0 = cb * 512 + tid;
    int c1 = c0 + 256;
    bool q0 = c0 < F_OUT, q1 = c1 < F_OUT;
    float b0 = q0 ? b[c0] : 0.f;
    float b1 = q1 ? b[c1] : 0.f;
    float mx0 = 0.f, mx1 = 0.f, sm0 = 0.f, sm1 = 0.f;
    int s = offs[g], e = offs[g + 1];
    for (int n0 = s; n0 < e; n0 += TILE) {
        int nvalid = e - n0; if (nvalid > TILE) nvalid = TILE;
        __syncthreads();
        if (nvalid < TILE) {
            for (int idx = tid; idx < F_IN * TILE; idx += 256)
                Vt[idx % F_IN][idx / F_IN] = 0.f;
            __syncthreads();
        }
        int total = nvalid * F_IN;
        const float* hs = h + (size_t)n0 * F_IN;
        const float* as = agg + (size_t)n0 * F_IN;
        for (int f = tid; f < total; f += 256)
            Vt[f % F_IN][f / F_IN] = hs[f] + as[f];
        __syncthreads();
        float acc0[TILE], acc1[TILE];
        #pragma unroll
        for (int n = 0; n < TILE; ++n) { acc0[n] = 0.f; acc1[n] = 0.f; }
        for (int k = 0; k < F_IN; ++k) {
            float w0 = q0 ? W[(size_t)k * F_OUT + c0] : 0.f;
            float w1 = q1 ? W[(size_t)k * F_OUT + c1] : 0.f;
            const float4* row = (const float4*)&Vt[k][0];
            #pragma unroll
            for (int q = 0; q < TILE / 4; ++q) {
                float4 a = row[q];
                acc0[q * 4 + 0] += a.x * w0;  acc1[q * 4 + 0] += a.x * w1;
                acc0[q * 4 + 1] += a.y * w0;  acc1[q * 4 + 1] += a.y * w1;
                acc0[q * 4 + 2] += a.z * w0;  acc1[q * 4 + 2] += a.z * w1;
                acc0[q * 4 + 3] += a.w * w0;  acc1[q * 4 + 3] += a.w * w1;
            }
        }
        for (int n = 0; n < nvalid; ++n) {
            float u0 = fmaxf(acc0[n] + b0, 0.f);
            float u1 = fmaxf(acc1[n] + b1, 0.f);
            mx0 = fmaxf(mx0, u0);  sm0 += u0;
            mx1 = fmaxf(mx1, u1);  sm1 += u1;
        }
    }
    int ng = e - s;
    float den = (float)(ng > 0 ? ng : 1);
    float* pg = p + (size_t)g * (2 * F_OUT);
    if (q0) { pg[c0] = mx0; pg[F_OUT + c0] = sm0 / den; }
    if (q1) { pg[c1] = mx1; pg[F_OUT + c1] = sm1 / den; }
}

// ---- dense FC: C[M,N] = (relu?)(A[M,K] @ W[K,N] + b) ----------------------
// 32 rows x 64 cols per block; 256 threads = 64 cols x 4 row-groups x 8 rows.
template<bool RELU>
__global__ __launch_bounds__(256) void fc_kernel(
        const float* __restrict__ A, const float* __restrict__ W,
        const float* __restrict__ b, float* __restrict__ C,
        int M, int K, int N) {
    constexpr int KT = 64;
    __shared__ __align__(16) float At[KT][36];
    int nb = N >> 6;
    int cb = blockIdx.x % nb;
    int rb = blockIdx.x / nb;
    int row0 = rb * 32;
    int col = (cb << 6) + (threadIdx.x & 63);
    int rg = threadIdx.x >> 6;           // 0..3, rows rg*8..rg*8+7
    float acc[8];
    #pragma unroll
    for (int r = 0; r < 8; ++r) acc[r] = 0.f;
    for (int k0 = 0; k0 < K; k0 += KT) {
        int kt = K - k0; if (kt > KT) kt = KT;
        __syncthreads();
        for (int idx = threadIdx.x; idx < 32 * KT; idx += 256) {
            int r = idx >> 6, kl = idx & 63;
            if (kl < kt) At[kl][r] = A[(size_t)(row0 + r) * K + k0 + kl];
        }
        __syncthreads();
        for (int kl = 0; kl < kt; ++kl) {
            float w = W[(size_t)(k0 + kl) * N + col];
            const float4* ar = (const float4*)&At[kl][rg * 8];
            float4 a0 = ar[0], a1 = ar[1];
            acc[0] += a0.x * w;  acc[1] += a0.y * w;
            acc[2] += a0.z * w;  acc[3] += a0.w * w;
            acc[4] += a1.x * w;  acc[5] += a1.y * w;
            acc[6] += a1.z * w;  acc[7] += a1.w * w;
        }
    }
    float bb = b[col];
    #pragma unroll
    for (int r = 0; r < 8; ++r) {
        float v = acc[r] + bb;
        if (RELU) v = fmaxf(v, 0.f);
        C[(size_t)(row0 + rg * 8 + r) * N + col] = v;
    }
}

// ---- final head: z[row] = dot(A[row,:], w) + b[0], K == 256 ----------------
__global__ __launch_bounds__(256) void final_dot_kernel(
        const float* __restrict__ A, const float* __restrict__ w,
        const float* __restrict__ b, float* __restrict__ z, int K) {
    int row = blockIdx.x;
    int tid = threadIdx.x;
    float v = (tid < K) ? A[(size_t)row * K + tid] * w[tid] : 0.f;
    #pragma unroll
    for (int o = 32; o > 0; o >>= 1) v += __shfl_down(v, o, 64);
    __shared__ float red[4];
    if ((tid & 63) == 0) red[tid >> 6] = v;
    __syncthreads();
    if (tid == 0) z[row] = red[0] + red[1] + red[2] + red[3] + b[0];
}

// ---------------------------------------------------------------------------
static inline int cdiv(int a, int b) { return (a + b - 1) / b; }

template<int F, int FO, int CB, int BD_LIN>
static void run_branch(const float* feat, const int* ei, int E, int N,
                       const int* seg,
                       const float* W1, const float* b1,
                       const float* W2, const float* b2,
                       const float* fw1, const float* fb1,
                       const float* fw2, const float* fb2,
                       const float* hw1, const float* hb1,
                       const float* hw2, const float* hb2,
                       float* agg, float* h1, float* p, float* t1, float* t2,
                       int* cnt, int* offs, int* deg, int* rowoff, int* cursor,
                       int* csr, int* bsum,
                       float* xg_out, float* z_out, hipStream_t stream) {
    // graph segment offsets
    hipMemsetAsync(cnt, 0, NG * sizeof(int), stream);
    hist_kernel<<<cdiv(N, 256), 256, 0, stream>>>(seg, N, cnt);
    seg_scan_kernel<<<1, 64, 0, stream>>>(cnt, offs);

    // CSR build (bucket edges by dst, reused for both GIN layers)
    hipMemsetAsync(deg, 0, N * sizeof(int), stream);
    deg_kernel<<<cdiv(E, 256), 256, 0, stream>>>(ei, E, deg);
    int nb = cdiv(N, 1024);
    scan1_kernel<<<nb, 256, 0, stream>>>(deg, N, rowoff, bsum);
    scan2_kernel<<<1, 64, 0, stream>>>(bsum, nb);
    scan3_kernel<<<cdiv(N, 256), 256, 0, stream>>>(rowoff, bsum, N, E);
    copy_kernel<<<cdiv(N, 256), 256, 0, stream>>>(cursor, rowoff, N);
    fill_csr_kernel<<<cdiv(E, 256), 256, 0, stream>>>(ei, E, cursor, csr);

    // GIN layer 1
    gather_kernel<F><<<cdiv(N, 4), 256, 0, stream>>>(feat, csr, rowoff, agg, N);
    gin_linear_kernel<F, BD_LIN><<<cdiv(N, 32), BD_LIN, 0, stream>>>(feat, agg, W1, b1, h1, N);

    // GIN layer 2 fused with pooling
    gather_kernel<F><<<cdiv(N, 4), 256, 0, stream>>>(h1, csr, rowoff, agg, N);
    gin_pool_kernel<F, FO, CB><<<NG * CB, 256, 0, stream>>>(h1, agg, W2, b2, offs, p);

    // FC heads
    const int Kfc = 2 * FO;
    fc_kernel<true ><<<(NG / 32) * (1024 >> 6), 256, 0, stream>>>(p,  fw1, fb1, t1, NG, Kfc,  1024);
    fc_kernel<false><<<(NG / 32) * ( 512 >> 6), 256, 0, stream>>>(t1, fw2, fb2, xg_out, NG, 1024, 512);
    fc_kernel<true ><<<(NG / 32) * ( 256 >> 6), 256, 0, stream>>>(xg_out, hw1, hb1, t2, NG, 512, 256);
    final_dot_kernel<<<NG, 256, 0, stream>>>(t2, hw2, hb2, z_out, 256);
}

extern "C" void kernel_launch(void* const* d_in, const int* in_sizes, int n_in,
                              void* d_out, int out_size, void* d_ws, size_t ws_size,
                              hipStream_t stream) {
    (void)n_in; (void)out_size; (void)ws_size;
    const float* x      = (const float*)d_in[1];
    const int*   ei     = (const int*)  d_in[2];
    const int*   batch  = (const int*)  d_in[3];
    const float* a      = (const float*)d_in[4];
    const int*   ed     = (const int*)  d_in[5];
    const int*   c      = (const int*)  d_in[6];
    const float* W1  = (const float*)d_in[7],  *b1  = (const float*)d_in[8];
    const float* W2  = (const float*)d_in[9],  *b2  = (const float*)d_in[10];
    const float* W3  = (const float*)d_in[11], *b3  = (const float*)d_in[12];
    const float* W4  = (const float*)d_in[13], *b4  = (const float*)d_in[14];
    const float* fg_w1  = (const float*)d_in[15], *fg_b1  = (const float*)d_in[16];
    const float* fg_w2  = (const float*)d_in[17], *fg_b2  = (const float*)d_in[18];
    const float* fg1_w1 = (const float*)d_in[19], *fg1_b1 = (const float*)d_in[20];
    const float* fg1_w2 = (const float*)d_in[21], *fg1_b2 = (const float*)d_in[22];
    const float* ff_w1  = (const float*)d_in[23], *ff_b1  = (const float*)d_in[24];
    const float* ff_w2  = (const float*)d_in[25], *ff_b2  = (const float*)d_in[26];
    const float* ff1_w1 = (const float*)d_in[27], *ff1_b1 = (const float*)d_in[28];
    const float* ff1_w2 = (const float*)d_in[29], *ff1_b2 = (const float*)d_in[30];

    const int N1 = in_sizes[1] / 93;
    const int E1 = in_sizes[2] / 2;
    const int N2 = in_sizes[4] / 43;
    const int E2 = in_sizes[5] / 2;

    float* out = (float*)d_out;
    float* z   = out;                       // [256]
    float* xg  = out + 256;                 // [256,512]
    float* xg1 = out + 256 + 256 * 512;     // [256,512]
    float* z1  = out + 256 + 2 * 256 * 512; // [256]

    // workspace carve-out (~43 MB)
    char* wsb = (char*)d_ws;
    size_t off = 0;
    auto carve = [&](size_t bytes) {
        void* ptr = wsb + off;
        off = (off + bytes + 255) & ~(size_t)255;
        return ptr;
    };
    float* agg = (float*)carve((size_t)N1 * 93 * sizeof(float));
    float* h1  = (float*)carve((size_t)N1 * 93 * sizeof(float));
    float* p   = (float*)carve((size_t)NG * 1860 * sizeof(float));
    float* t1  = (float*)carve((size_t)NG * 1024 * sizeof(float));
    float* t2  = (float*)carve((size_t)NG * 256 * sizeof(float));
    int*   cnt    = (int*)carve(NG * sizeof(int));
    int*   offs   = (int*)carve((NG + 1) * sizeof(int));
    int*   deg    = (int*)carve((size_t)N1 * sizeof(int));
    int*   rowoff = (int*)carve((size_t)(N1 + 1) * sizeof(int));
    int*   cursor = (int*)carve((size_t)N1 * sizeof(int));
    int*   csr    = (int*)carve((size_t)E1 * sizeof(int));
    int*   bsum   = (int*)carve(128 * sizeof(int));

    // branch 1: 93 -> 93 -> 930, pool 1860
    run_branch<93, 930, 2, 128>(x, ei, E1, N1, batch,
                                W1, b1, W2, b2,
                                fg_w1, fg_b1, fg_w2, fg_b2,
                                ff_w1, ff_b1, ff_w2, ff_b2,
                                agg, h1, p, t1, t2,
                                cnt, offs, deg, rowoff, cursor, csr, bsum,
                                xg, z, stream);

    // branch 2: 43 -> 43 -> 430, pool 860 (reuses all scratch)
    run_branch<43, 430, 1, 64>(a, ed, E2, N2, c,
                               W3, b3, W4, b4,
                               fg1_w1, fg1_b1, fg1_w2, fg1_b2,
                               ff1_w1, ff1_b1, ff1_w2, ff1_b2,
                               agg, h1, p, t1, t2,
                               cnt, offs, deg, rowoff, cursor, csr, bsum,
                               xg1, z1, stream);
}

// Round 3
// 1162.602 us; speedup vs baseline: 2.4441x; 2.3876x over previous
//
#include <hip/hip_runtime.h>

// ---------------------------------------------------------------------------
// Round 3: split-K latency-tolerant FC stack (the R2 profile showed fc_kernel
// at 650us with VALUBusy 1.3% / occupancy 6% -- pure latency stall), fused
// final head. CSR gather + fused GIN2+pool kept from R2.
// ---------------------------------------------------------------------------

static constexpr int NG = 256;  // number of graphs

// ---- segment bookkeeping ---------------------------------------------------
__global__ void hist_kernel(const int* __restrict__ seg, int N, int* __restrict__ cnt) {
    int i = blockIdx.x * blockDim.x + threadIdx.x;
    if (i < N) atomicAdd(&cnt[seg[i]], 1);
}

__global__ void seg_scan_kernel(const int* __restrict__ cnt, int* __restrict__ offs) {
    if (threadIdx.x == 0) {
        int acc = 0;
        for (int g = 0; g < NG; ++g) { offs[g] = acc; acc += cnt[g]; }
        offs[NG] = acc;
    }
}

// ---- CSR build: histogram dst -> prefix scan -> fill ----------------------
__global__ void deg_kernel(const int* __restrict__ ei, int E, int* __restrict__ deg) {
    int e = blockIdx.x * blockDim.x + threadIdx.x;
    if (e < E) atomicAdd(&deg[ei[E + e]], 1);   // dst = ei[E+e]
}

__global__ __launch_bounds__(256) void scan1_kernel(const int* __restrict__ deg, int N,
                                                    int* __restrict__ excl,
                                                    int* __restrict__ bsum) {
    __shared__ int sh[256];
    int base = blockIdx.x * 1024;
    int t = threadIdx.x;
    int v[4];
    int s = 0;
    #pragma unroll
    for (int i = 0; i < 4; ++i) {
        int idx = base + t * 4 + i;
        v[i] = s;
        s += (idx < N) ? deg[idx] : 0;
    }
    sh[t] = s;
    __syncthreads();
    for (int off = 1; off < 256; off <<= 1) {
        int xv = (t >= off) ? sh[t - off] : 0;
        __syncthreads();
        sh[t] += xv;
        __syncthreads();
    }
    int texcl = (t > 0) ? sh[t - 1] : 0;
    #pragma unroll
    for (int i = 0; i < 4; ++i) {
        int idx = base + t * 4 + i;
        if (idx < N) excl[idx] = texcl + v[i];
    }
    if (t == 255) bsum[blockIdx.x] = sh[255];
}

__global__ void scan2_kernel(int* __restrict__ bsum, int nb) {
    if (threadIdx.x == 0) {
        int acc = 0;
        for (int i = 0; i < nb; ++i) { int t = bsum[i]; bsum[i] = acc; acc += t; }
    }
}

__global__ void scan3_kernel(int* __restrict__ excl, const int* __restrict__ bsum,
                             int N, int E) {
    int i = blockIdx.x * blockDim.x + threadIdx.x;
    if (i < N) excl[i] += bsum[i >> 10];
    if (i == 0) excl[N] = E;
}

__global__ void copy_kernel(int* __restrict__ dst, const int* __restrict__ src, int N) {
    int i = blockIdx.x * blockDim.x + threadIdx.x;
    if (i < N) dst[i] = src[i];
}

__global__ void fill_csr_kernel(const int* __restrict__ ei, int E,
                                int* __restrict__ cursor, int* __restrict__ csr) {
    int e = blockIdx.x * blockDim.x + threadIdx.x;
    if (e < E) {
        int dst = ei[E + e];
        int pos = atomicAdd(&cursor[dst], 1);
        csr[pos] = ei[e];                    // src
    }
}

// ---- gather: agg[n] = sum_{e: dst==n} x[src_e]  (wave per node) -----------
template<int F>
__global__ __launch_bounds__(256) void gather_kernel(const float* __restrict__ x,
        const int* __restrict__ csr, const int* __restrict__ ro,
        float* __restrict__ agg, int N) {
    int wave = (blockIdx.x * 256 + threadIdx.x) >> 6;
    int lane = threadIdx.x & 63;
    if (wave >= N) return;
    int s = ro[wave], e = ro[wave + 1];
    float a0 = 0.f, a1 = 0.f;
    const bool l0 = lane < F;
    const bool l1 = (lane + 64) < F;
    for (int i = s; i < e; ++i) {
        const float* row = x + (size_t)csr[i] * F;
        if (l0) a0 += row[lane];
        if (l1) a1 += row[lane + 64];
    }
    float* o = agg + (size_t)wave * F;
    if (l0) o[lane] = a0;
    if (l1) o[lane + 64] = a1;
}

// ---- GIN layer 1: out = relu((x+agg) @ W + b), F -> F ---------------------
template<int F, int BD>
__global__ __launch_bounds__(BD) void gin_linear_kernel(
        const float* __restrict__ x, const float* __restrict__ agg,
        const float* __restrict__ W, const float* __restrict__ b,
        float* __restrict__ out, int N) {
    constexpr int TILE = 32, PAD = 36;
    __shared__ __align__(16) float Vt[F][PAD];
    int node0 = blockIdx.x * TILE;
    if (node0 >= N) return;
    int nvalid = N - node0; if (nvalid > TILE) nvalid = TILE;
    if (nvalid < TILE) {
        for (int idx = threadIdx.x; idx < F * TILE; idx += BD)
            Vt[idx % F][idx / F] = 0.f;
        __syncthreads();
    }
    int total = nvalid * F;
    const float* xs = x + (size_t)node0 * F;
    const float* as = agg + (size_t)node0 * F;
    for (int f = threadIdx.x; f < total; f += BD)
        Vt[f % F][f / F] = xs[f] + as[f];
    __syncthreads();
    int j = threadIdx.x;
    if (j < F) {
        float acc[TILE];
        #pragma unroll
        for (int n = 0; n < TILE; ++n) acc[n] = 0.f;
        for (int k = 0; k < F; ++k) {
            float w = W[k * F + j];
            const float4* row = (const float4*)&Vt[k][0];
            #pragma unroll
            for (int q = 0; q < TILE / 4; ++q) {
                float4 a = row[q];
                acc[q * 4 + 0] += a.x * w;
                acc[q * 4 + 1] += a.y * w;
                acc[q * 4 + 2] += a.z * w;
                acc[q * 4 + 3] += a.w * w;
            }
        }
        float bj = b[j];
        for (int n = 0; n < nvalid; ++n)
            out[(size_t)(node0 + n) * F + j] = fmaxf(acc[n] + bj, 0.f);
    }
}

// ---- fused GIN layer 2 + max/mean pool ------------------------------------
template<int F_IN, int F_OUT, int CB>
__global__ __launch_bounds__(256) void gin_pool_kernel(
        const float* __restrict__ h, const float* __restrict__ agg,
        const float* __restrict__ W, const float* __restrict__ b,
        const int* __restrict__ offs, float* __restrict__ p) {
    constexpr int TILE = 32, PAD = 36;
    __shared__ __align__(16) float Vt[F_IN][PAD];
    int g  = blockIdx.x / CB;
    int cb = blockIdx.x % CB;
    int tid = threadIdx.x;
    int c0 = cb * 512 + tid;
    int c1 = c0 + 256;
    bool q0 = c0 < F_OUT, q1 = c1 < F_OUT;
    float b0 = q0 ? b[c0] : 0.f;
    float b1 = q1 ? b[c1] : 0.f;
    float mx0 = 0.f, mx1 = 0.f, sm0 = 0.f, sm1 = 0.f;
    int s = offs[g], e = offs[g + 1];
    for (int n0 = s; n0 < e; n0 += TILE) {
        int nvalid = e - n0; if (nvalid > TILE) nvalid = TILE;
        __syncthreads();
        if (nvalid < TILE) {
            for (int idx = tid; idx < F_IN * TILE; idx += 256)
                Vt[idx % F_IN][idx / F_IN] = 0.f;
            __syncthreads();
        }
        int total = nvalid * F_IN;
        const float* hs = h + (size_t)n0 * F_IN;
        const float* as = agg + (size_t)n0 * F_IN;
        for (int f = tid; f < total; f += 256)
            Vt[f % F_IN][f / F_IN] = hs[f] + as[f];
        __syncthreads();
        float acc0[TILE], acc1[TILE];
        #pragma unroll
        for (int n = 0; n < TILE; ++n) { acc0[n] = 0.f; acc1[n] = 0.f; }
        for (int k = 0; k < F_IN; ++k) {
            float w0 = q0 ? W[(size_t)k * F_OUT + c0] : 0.f;
            float w1 = q1 ? W[(size_t)k * F_OUT + c1] : 0.f;
            const float4* row = (const float4*)&Vt[k][0];
            #pragma unroll
            for (int q = 0; q < TILE / 4; ++q) {
                float4 a = row[q];
                acc0[q * 4 + 0] += a.x * w0;  acc1[q * 4 + 0] += a.x * w1;
                acc0[q * 4 + 1] += a.y * w0;  acc1[q * 4 + 1] += a.y * w1;
                acc0[q * 4 + 2] += a.z * w0;  acc1[q * 4 + 2] += a.z * w1;
                acc0[q * 4 + 3] += a.w * w0;  acc1[q * 4 + 3] += a.w * w1;
            }
        }
        for (int n = 0; n < nvalid; ++n) {
            float u0 = fmaxf(acc0[n] + b0, 0.f);
            float u1 = fmaxf(acc1[n] + b1, 0.f);
            mx0 = fmaxf(mx0, u0);  sm0 += u0;
            mx1 = fmaxf(mx1, u1);  sm1 += u1;
        }
    }
    int ng = e - s;
    float den = (float)(ng > 0 ? ng : 1);
    float* pg = p + (size_t)g * (2 * F_OUT);
    if (q0) { pg[c0] = mx0; pg[F_OUT + c0] = sm0 / den; }
    if (q1) { pg[c1] = mx1; pg[F_OUT + c1] = sm1 / den; }
}

// ---- split-K dense FC: C[M,N] = (relu?)(A[M,K] @ W[K,N] + b) --------------
// block = 256 thr = 64 cols x KG=4 k-groups; RT=4 rows of A staged in LDS.
// K is a template param -> fixed trip count -> unrolled, pipelined W loads.
template<int K, int KG, int RT, bool RELU>
__global__ __launch_bounds__(256) void fc_kernel(
        const float* __restrict__ A, const float* __restrict__ W,
        const float* __restrict__ b, float* __restrict__ C, int N) {
    static_assert(K % KG == 0, "");
    constexpr int CT = 256 / KG;           // cols per block
    constexpr int KCH = K / KG;
    __shared__ float As[RT][K];
    __shared__ float red[256][RT + 1];     // +1 pad: conflict-free
    int nb = N / CT;
    int cb = blockIdx.x % nb;
    int rb = blockIdx.x / nb;
    int row0 = rb * RT;
    int t = threadIdx.x;
    int cl = t % CT;
    int kg = t / CT;
    int col = cb * CT + cl;
    #pragma unroll
    for (int r = 0; r < RT; ++r)
        for (int k = t; k < K; k += 256)
            As[r][k] = A[(size_t)(row0 + r) * K + k];
    __syncthreads();
    float acc[RT];
    #pragma unroll
    for (int r = 0; r < RT; ++r) acc[r] = 0.f;
    const float* Wp = W + (size_t)(kg * KCH) * N + col;
    #pragma unroll 4
    for (int i = 0; i < KCH; ++i) {
        float w = Wp[(size_t)i * N];
        int k = kg * KCH + i;
        #pragma unroll
        for (int r = 0; r < RT; ++r) acc[r] += As[r][k] * w;
    }
    #pragma unroll
    for (int r = 0; r < RT; ++r) red[t][r] = acc[r];
    __syncthreads();
    if (kg == 0) {
        #pragma unroll
        for (int r = 0; r < RT; ++r) {
            float v = acc[r];
            #pragma unroll
            for (int g = 1; g < KG; ++g) v += red[g * CT + cl][r];
            v += b[col];
            if (RELU) v = fmaxf(v, 0.f);
            C[(size_t)(row0 + r) * N + col] = v;
        }
    }
}

// ---- fused final head: z[row] = relu(A[row]@W1+b1) . w2 + b2 --------------
// A: [M,512], W1: [512,256], w2: [256]. One block per row.
__global__ __launch_bounds__(256) void head_kernel(
        const float* __restrict__ A, const float* __restrict__ W1,
        const float* __restrict__ b1, const float* __restrict__ w2,
        const float* __restrict__ b2, float* __restrict__ z) {
    __shared__ float As[512];
    __shared__ float red[4];
    int row = blockIdx.x;
    int t = threadIdx.x;
    for (int k = t; k < 512; k += 256) As[k] = A[(size_t)row * 512 + k];
    __syncthreads();
    float acc = 0.f;
    #pragma unroll 8
    for (int k = 0; k < 512; ++k)
        acc += As[k] * W1[(size_t)k * 256 + t];
    float h = fmaxf(acc + b1[t], 0.f);
    float v = h * w2[t];
    #pragma unroll
    for (int o = 32; o > 0; o >>= 1) v += __shfl_down(v, o, 64);
    if ((t & 63) == 0) red[t >> 6] = v;
    __syncthreads();
    if (t == 0) z[row] = red[0] + red[1] + red[2] + red[3] + b2[0];
}

// ---------------------------------------------------------------------------
static inline int cdiv(int a, int b) { return (a + b - 1) / b; }

template<int F, int FO, int CB, int BD_LIN, int KFC>
static void run_branch(const float* feat, const int* ei, int E, int N,
                       const int* seg,
                       const float* W1, const float* b1,
                       const float* W2, const float* b2,
                       const float* fw1, const float* fb1,
                       const float* fw2, const float* fb2,
                       const float* hw1, const float* hb1,
                       const float* hw2, const float* hb2,
                       float* agg, float* h1, float* p, float* t1,
                       int* cnt, int* offs, int* deg, int* rowoff, int* cursor,
                       int* csr, int* bsum,
                       float* xg_out, float* z_out, hipStream_t stream) {
    // graph segment offsets
    hipMemsetAsync(cnt, 0, NG * sizeof(int), stream);
    hist_kernel<<<cdiv(N, 256), 256, 0, stream>>>(seg, N, cnt);
    seg_scan_kernel<<<1, 64, 0, stream>>>(cnt, offs);

    // CSR build (bucket edges by dst, reused for both GIN layers)
    hipMemsetAsync(deg, 0, N * sizeof(int), stream);
    deg_kernel<<<cdiv(E, 256), 256, 0, stream>>>(ei, E, deg);
    int nb = cdiv(N, 1024);
    scan1_kernel<<<nb, 256, 0, stream>>>(deg, N, rowoff, bsum);
    scan2_kernel<<<1, 64, 0, stream>>>(bsum, nb);
    scan3_kernel<<<cdiv(N, 256), 256, 0, stream>>>(rowoff, bsum, N, E);
    copy_kernel<<<cdiv(N, 256), 256, 0, stream>>>(cursor, rowoff, N);
    fill_csr_kernel<<<cdiv(E, 256), 256, 0, stream>>>(ei, E, cursor, csr);

    // GIN layer 1
    gather_kernel<F><<<cdiv(N, 4), 256, 0, stream>>>(feat, csr, rowoff, agg, N);
    gin_linear_kernel<F, BD_LIN><<<cdiv(N, 32), BD_LIN, 0, stream>>>(feat, agg, W1, b1, h1, N);

    // GIN layer 2 fused with pooling
    gather_kernel<F><<<cdiv(N, 4), 256, 0, stream>>>(h1, csr, rowoff, agg, N);
    gin_pool_kernel<F, FO, CB><<<NG * CB, 256, 0, stream>>>(h1, agg, W2, b2, offs, p);

    // FC heads (split-K): p[NG,KFC] -> t1[NG,1024] -> xg[NG,512] -> z[NG]
    fc_kernel<KFC,  4, 4, true ><<<(NG / 4) * (1024 / 64), 256, 0, stream>>>(p,  fw1, fb1, t1, 1024);
    fc_kernel<1024, 4, 4, false><<<(NG / 4) * ( 512 / 64), 256, 0, stream>>>(t1, fw2, fb2, xg_out, 512);
    head_kernel<<<NG, 256, 0, stream>>>(xg_out, hw1, hb1, hw2, hb2, z_out);
}

extern "C" void kernel_launch(void* const* d_in, const int* in_sizes, int n_in,
                              void* d_out, int out_size, void* d_ws, size_t ws_size,
                              hipStream_t stream) {
    (void)n_in; (void)out_size; (void)ws_size;
    const float* x      = (const float*)d_in[1];
    const int*   ei     = (const int*)  d_in[2];
    const int*   batch  = (const int*)  d_in[3];
    const float* a      = (const float*)d_in[4];
    const int*   ed     = (const int*)  d_in[5];
    const int*   c      = (const int*)  d_in[6];
    const float* W1  = (const float*)d_in[7],  *b1  = (const float*)d_in[8];
    const float* W2  = (const float*)d_in[9],  *b2  = (const float*)d_in[10];
    const float* W3  = (const float*)d_in[11], *b3  = (const float*)d_in[12];
    const float* W4  = (const float*)d_in[13], *b4  = (const float*)d_in[14];
    const float* fg_w1  = (const float*)d_in[15], *fg_b1  = (const float*)d_in[16];
    const float* fg_w2  = (const float*)d_in[17], *fg_b2  = (const float*)d_in[18];
    const float* fg1_w1 = (const float*)d_in[19], *fg1_b1 = (const float*)d_in[20];
    const float* fg1_w2 = (const float*)d_in[21], *fg1_b2 = (const float*)d_in[22];
    const float* ff_w1  = (const float*)d_in[23], *ff_b1  = (const float*)d_in[24];
    const float* ff_w2  = (const float*)d_in[25], *ff_b2  = (const float*)d_in[26];
    const float* ff1_w1 = (const float*)d_in[27], *ff1_b1 = (const float*)d_in[28];
    const float* ff1_w2 = (const float*)d_in[29], *ff1_b2 = (const float*)d_in[30];

    const int N1 = in_sizes[1] / 93;
    const int E1 = in_sizes[2] / 2;
    const int N2 = in_sizes[4] / 43;
    const int E2 = in_sizes[5] / 2;

    float* out = (float*)d_out;
    float* z   = out;                       // [256]
    float* xg  = out + 256;                 // [256,512]
    float* xg1 = out + 256 + 256 * 512;     // [256,512]
    float* z1  = out + 256 + 2 * 256 * 512; // [256]

    char* wsb = (char*)d_ws;
    size_t off = 0;
    auto carve = [&](size_t bytes) {
        void* ptr = wsb + off;
        off = (off + bytes + 255) & ~(size_t)255;
        return ptr;
    };
    float* agg = (float*)carve((size_t)N1 * 93 * sizeof(float));
    float* h1  = (float*)carve((size_t)N1 * 93 * sizeof(float));
    float* p   = (float*)carve((size_t)NG * 1860 * sizeof(float));
    float* t1  = (float*)carve((size_t)NG * 1024 * sizeof(float));
    int*   cnt    = (int*)carve(NG * sizeof(int));
    int*   offs   = (int*)carve((NG + 1) * sizeof(int));
    int*   deg    = (int*)carve((size_t)N1 * sizeof(int));
    int*   rowoff = (int*)carve((size_t)(N1 + 1) * sizeof(int));
    int*   cursor = (int*)carve((size_t)N1 * sizeof(int));
    int*   csr    = (int*)carve((size_t)E1 * sizeof(int));
    int*   bsum   = (int*)carve(128 * sizeof(int));

    // branch 1: 93 -> 93 -> 930, pool 1860
    run_branch<93, 930, 2, 128, 1860>(x, ei, E1, N1, batch,
                                W1, b1, W2, b2,
                                fg_w1, fg_b1, fg_w2, fg_b2,
                                ff_w1, ff_b1, ff_w2, ff_b2,
                                agg, h1, p, t1,
                                cnt, offs, deg, rowoff, cursor, csr, bsum,
                                xg, z, stream);

    // branch 2: 43 -> 43 -> 430, pool 860 (reuses all scratch)
    run_branch<43, 430, 1, 64, 860>(a, ed, E2, N2, c,
                               W3, b3, W4, b4,
                               fg1_w1, fg1_b1, fg1_w2, fg1_b2,
                               ff1_w1, ff1_b1, ff1_w2, ff1_b2,
                               agg, h1, p, t1,
                               cnt, offs, deg, rowoff, cursor, csr, bsum,
                               xg1, z1, stream);
}

// Round 4
// 964.735 us; speedup vs baseline: 2.9453x; 1.2051x over previous
//
#include <hip/hip_runtime.h>

// ---------------------------------------------------------------------------
// Round 4: bf16-MFMA fused GIN2+pool (R3 profile: gin_pool 245us, VALUBusy 37%,
// MfmaUtil 0, occupancy grid-capped). W2 repacked to B-frag layout once per
// launch; A-frags held in registers across N-tiles; partial pools + reduce.
// ---------------------------------------------------------------------------

static constexpr int NG = 256;  // number of graphs

typedef short  short8  __attribute__((ext_vector_type(8)));
typedef float  floatx4 __attribute__((ext_vector_type(4)));

__device__ __forceinline__ short f2bf(float f) {
    unsigned u = __float_as_uint(f);
    u += 0x7fff + ((u >> 16) & 1);          // RNE to bf16
    return (short)(u >> 16);
}

// ---- segment bookkeeping ---------------------------------------------------
__global__ void hist_kernel(const int* __restrict__ seg, int N, int* __restrict__ cnt) {
    int i = blockIdx.x * blockDim.x + threadIdx.x;
    if (i < N) atomicAdd(&cnt[seg[i]], 1);
}

__global__ void seg_scan_kernel(const int* __restrict__ cnt, int* __restrict__ offs) {
    if (threadIdx.x == 0) {
        int acc = 0;
        for (int g = 0; g < NG; ++g) { offs[g] = acc; acc += cnt[g]; }
        offs[NG] = acc;
    }
}

// ---- CSR build: histogram dst -> prefix scan -> fill ----------------------
__global__ void deg_kernel(const int* __restrict__ ei, int E, int* __restrict__ deg) {
    int e = blockIdx.x * blockDim.x + threadIdx.x;
    if (e < E) atomicAdd(&deg[ei[E + e]], 1);   // dst = ei[E+e]
}

__global__ __launch_bounds__(256) void scan1_kernel(const int* __restrict__ deg, int N,
                                                    int* __restrict__ excl,
                                                    int* __restrict__ bsum) {
    __shared__ int sh[256];
    int base = blockIdx.x * 1024;
    int t = threadIdx.x;
    int v[4];
    int s = 0;
    #pragma unroll
    for (int i = 0; i < 4; ++i) {
        int idx = base + t * 4 + i;
        v[i] = s;
        s += (idx < N) ? deg[idx] : 0;
    }
    sh[t] = s;
    __syncthreads();
    for (int off = 1; off < 256; off <<= 1) {
        int xv = (t >= off) ? sh[t - off] : 0;
        __syncthreads();
        sh[t] += xv;
        __syncthreads();
    }
    int texcl = (t > 0) ? sh[t - 1] : 0;
    #pragma unroll
    for (int i = 0; i < 4; ++i) {
        int idx = base + t * 4 + i;
        if (idx < N) excl[idx] = texcl + v[i];
    }
    if (t == 255) bsum[blockIdx.x] = sh[255];
}

__global__ void scan2_kernel(int* __restrict__ bsum, int nb) {
    if (threadIdx.x == 0) {
        int acc = 0;
        for (int i = 0; i < nb; ++i) { int t = bsum[i]; bsum[i] = acc; acc += t; }
    }
}

__global__ void scan3_kernel(int* __restrict__ excl, const int* __restrict__ bsum,
                             int N, int E) {
    int i = blockIdx.x * blockDim.x + threadIdx.x;
    if (i < N) excl[i] += bsum[i >> 10];
    if (i == 0) excl[N] = E;
}

__global__ void copy_kernel(int* __restrict__ dst, const int* __restrict__ src, int N) {
    int i = blockIdx.x * blockDim.x + threadIdx.x;
    if (i < N) dst[i] = src[i];
}

__global__ void fill_csr_kernel(const int* __restrict__ ei, int E,
                                int* __restrict__ cursor, int* __restrict__ csr) {
    int e = blockIdx.x * blockDim.x + threadIdx.x;
    if (e < E) {
        int dst = ei[E + e];
        int pos = atomicAdd(&cursor[dst], 1);
        csr[pos] = ei[e];                    // src
    }
}

// ---- gather: agg[n] = sum_{e: dst==n} x[src_e]  (wave per node) -----------
template<int F>
__global__ __launch_bounds__(256) void gather_kernel(const float* __restrict__ x,
        const int* __restrict__ csr, const int* __restrict__ ro,
        float* __restrict__ agg, int N) {
    int wave = (blockIdx.x * 256 + threadIdx.x) >> 6;
    int lane = threadIdx.x & 63;
    if (wave >= N) return;
    int s = ro[wave], e = ro[wave + 1];
    float a0 = 0.f, a1 = 0.f;
    const bool l0 = lane < F;
    const bool l1 = (lane + 64) < F;
    for (int i = s; i < e; ++i) {
        const float* row = x + (size_t)csr[i] * F;
        if (l0) a0 += row[lane];
        if (l1) a1 += row[lane + 64];
    }
    float* o = agg + (size_t)wave * F;
    if (l0) o[lane] = a0;
    if (l1) o[lane + 64] = a1;
}

// ---- GIN layer 1: out = relu((x+agg) @ W + b), F -> F ---------------------
template<int F, int BD>
__global__ __launch_bounds__(BD) void gin_linear_kernel(
        const float* __restrict__ x, const float* __restrict__ agg,
        const float* __restrict__ W, const float* __restrict__ b,
        float* __restrict__ out, int N) {
    constexpr int TILE = 32, PAD = 36;
    __shared__ __align__(16) float Vt[F][PAD];
    int node0 = blockIdx.x * TILE;
    if (node0 >= N) return;
    int nvalid = N - node0; if (nvalid > TILE) nvalid = TILE;
    if (nvalid < TILE) {
        for (int idx = threadIdx.x; idx < F * TILE; idx += BD)
            Vt[idx % F][idx / F] = 0.f;
        __syncthreads();
    }
    int total = nvalid * F;
    const float* xs = x + (size_t)node0 * F;
    const float* as = agg + (size_t)node0 * F;
    for (int f = threadIdx.x; f < total; f += BD)
        Vt[f % F][f / F] = xs[f] + as[f];
    __syncthreads();
    int j = threadIdx.x;
    if (j < F) {
        float acc[TILE];
        #pragma unroll
        for (int n = 0; n < TILE; ++n) acc[n] = 0.f;
        for (int k = 0; k < F; ++k) {
            float w = W[k * F + j];
            const float4* row = (const float4*)&Vt[k][0];
            #pragma unroll
            for (int q = 0; q < TILE / 4; ++q) {
                float4 a = row[q];
                acc[q * 4 + 0] += a.x * w;
                acc[q * 4 + 1] += a.y * w;
                acc[q * 4 + 2] += a.z * w;
                acc[q * 4 + 3] += a.w * w;
            }
        }
        float bj = b[j];
        for (int n = 0; n < nvalid; ++n)
            out[(size_t)(node0 + n) * F + j] = fmaxf(acc[n] + bj, 0.f);
    }
}

// ---- W repack for MFMA B-fragments: W[F][FO] fp32 -> Wb[NT*16][KP] bf16 ---
template<int F, int KP, int FO, int NT>
__global__ void repack_w_kernel(const float* __restrict__ W, short* __restrict__ Wb) {
    int id = blockIdx.x * blockDim.x + threadIdx.x;   // col index incl. pad
    if (id >= NT * 16) return;
    for (int k = 0; k < KP; ++k) {
        float v = (k < F && id < FO) ? W[(size_t)k * FO + id] : 0.f;
        Wb[(size_t)id * KP + k] = f2bf(v);
    }
}

// ---- fused GIN layer 2 + pool, bf16 MFMA ----------------------------------
// block = (graph g, node-split s); 4 waves stride the N-tiles.
// A-frags (64-node chunk) held in registers across all N-tiles.
// Partial [max|sum] pools -> ppmax/ppsum[(g*NS+s)][FO]; reduced afterwards.
template<int F, int KP, int FO, int NT, int NS>
__global__ __launch_bounds__(256) void gin_pool_mfma_kernel(
        const float* __restrict__ h, const float* __restrict__ agg,
        const short* __restrict__ Wb, const float* __restrict__ b,
        const int* __restrict__ offs,
        float* __restrict__ ppmax, float* __restrict__ ppsum) {
    constexpr int KK = KP / 32;
    __shared__ __align__(16) short Vb[64][KP];
    __shared__ float pmaxL[NT * 16];
    __shared__ float psumL[NT * 16];
    int g = blockIdx.x / NS;
    int s = blockIdx.x % NS;
    int tid = threadIdx.x;
    int wid = tid >> 6;
    int lane = tid & 63;
    int ln = lane & 15;
    int quad = lane >> 4;

    int gs0 = offs[g], ge0 = offs[g + 1];
    int per = (ge0 - gs0 + NS - 1) / NS;
    int gs = gs0 + s * per;
    int ge = gs + per; if (ge > ge0) ge = ge0;

    // init pools + zero K-pad columns of Vb (staging never writes them)
    for (int i = tid; i < NT * 16; i += 256) { pmaxL[i] = 0.f; psumL[i] = 0.f; }
    for (int i = tid; i < 64 * (KP - F); i += 256)
        Vb[i / (KP - F)][F + i % (KP - F)] = 0;

    for (int c0 = gs; c0 < ge; c0 += 64) {
        __syncthreads();   // pools/Vb ready; prev chunk's readers done
        int cvalid = ge - c0; if (cvalid > 64) cvalid = 64;
        // stage (h+agg) rows as bf16
        int nelem = cvalid * F;
        const float* hs = h + (size_t)c0 * F;
        const float* as = agg + (size_t)c0 * F;
        for (int idx = tid; idx < nelem; idx += 256)
            Vb[idx / F][idx % F] = f2bf(hs[idx] + as[idx]);
        __syncthreads();
        // A-fragments for 4 M-subtiles, all K-steps, held in VGPRs
        short8 afr[KK][4];
        #pragma unroll
        for (int kk = 0; kk < KK; ++kk)
            #pragma unroll
            for (int ms = 0; ms < 4; ++ms)
                afr[kk][ms] = *(const short8*)&Vb[ms * 16 + ln][kk * 32 + quad * 8];
        for (int nt = wid; nt < NT; nt += 4) {
            int col = nt * 16 + ln;
            float bcol = (col < FO) ? b[col] : 0.f;
            short8 bfr[KK];
            const short8* bp = (const short8*)(Wb + (size_t)col * KP + quad * 8);
            #pragma unroll
            for (int kk = 0; kk < KK; ++kk) bfr[kk] = bp[kk * 4];
            float cmx = 0.f, csm = 0.f;
            #pragma unroll
            for (int ms = 0; ms < 4; ++ms) {
                if (ms * 16 < cvalid) {
                    floatx4 acc = {0.f, 0.f, 0.f, 0.f};
                    #pragma unroll
                    for (int kk = 0; kk < KK; ++kk)
                        acc = __builtin_amdgcn_mfma_f32_16x16x32_bf16(
                                  afr[kk][ms], bfr[kk], acc, 0, 0, 0);
                    #pragma unroll
                    for (int r = 0; r < 4; ++r) {
                        int rowl = ms * 16 + quad * 4 + r;
                        float v = fmaxf(acc[r] + bcol, 0.f);
                        if (rowl < cvalid) { cmx = fmaxf(cmx, v); csm += v; }
                    }
                }
            }
            // reduce across the 4 row-quads (same col)
            cmx = fmaxf(cmx, __shfl_xor(cmx, 16, 64));
            cmx = fmaxf(cmx, __shfl_xor(cmx, 32, 64));
            csm += __shfl_xor(csm, 16, 64);
            csm += __shfl_xor(csm, 32, 64);
            if (quad == 0) {   // exclusive nt ownership per wave -> safe RMW
                int i = nt * 16 + ln;
                pmaxL[i] = fmaxf(pmaxL[i], cmx);
                psumL[i] += csm;
            }
        }
    }
    __syncthreads();
    float* om = ppmax + (size_t)(g * NS + s) * FO;
    float* os = ppsum + (size_t)(g * NS + s) * FO;
    for (int col = tid; col < FO; col += 256) { om[col] = pmaxL[col]; os[col] = psumL[col]; }
}

// ---- combine partial pools: p[g] = [max | sum/cnt] ------------------------
template<int FO, int NS>
__global__ __launch_bounds__(256) void pool_reduce_kernel(
        const float* __restrict__ ppmax, const float* __restrict__ ppsum,
        const int* __restrict__ offs, float* __restrict__ p) {
    int g = blockIdx.x;
    int cntg = offs[g + 1] - offs[g];
    float den = (float)(cntg > 0 ? cntg : 1);
    for (int col = threadIdx.x; col < FO; col += 256) {
        float m = 0.f, sm = 0.f;
        #pragma unroll
        for (int ss = 0; ss < NS; ++ss) {
            m = fmaxf(m, ppmax[(size_t)(g * NS + ss) * FO + col]);
            sm += ppsum[(size_t)(g * NS + ss) * FO + col];
        }
        p[(size_t)g * (2 * FO) + col] = m;
        p[(size_t)g * (2 * FO) + FO + col] = sm / den;
    }
}

// ---- split-K dense FC: C[M,N] = (relu?)(A[M,K] @ W[K,N] + b) --------------
template<int K, int KG, int RT, bool RELU>
__global__ __launch_bounds__(256) void fc_kernel(
        const float* __restrict__ A, const float* __restrict__ W,
        const float* __restrict__ b, float* __restrict__ C, int N) {
    static_assert(K % KG == 0, "");
    constexpr int CT = 256 / KG;           // cols per block
    constexpr int KCH = K / KG;
    __shared__ float As[RT][K];
    __shared__ float red[256][RT + 1];
    int nb = N / CT;
    int cb = blockIdx.x % nb;
    int rb = blockIdx.x / nb;
    int row0 = rb * RT;
    int t = threadIdx.x;
    int cl = t % CT;
    int kg = t / CT;
    int col = cb * CT + cl;
    #pragma unroll
    for (int r = 0; r < RT; ++r)
        for (int k = t; k < K; k += 256)
            As[r][k] = A[(size_t)(row0 + r) * K + k];
    __syncthreads();
    float acc[RT];
    #pragma unroll
    for (int r = 0; r < RT; ++r) acc[r] = 0.f;
    const float* Wp = W + (size_t)(kg * KCH) * N + col;
    #pragma unroll 4
    for (int i = 0; i < KCH; ++i) {
        float w = Wp[(size_t)i * N];
        int k = kg * KCH + i;
        #pragma unroll
        for (int r = 0; r < RT; ++r) acc[r] += As[r][k] * w;
    }
    #pragma unroll
    for (int r = 0; r < RT; ++r) red[t][r] = acc[r];
    __syncthreads();
    if (kg == 0) {
        #pragma unroll
        for (int r = 0; r < RT; ++r) {
            float v = acc[r];
            #pragma unroll
            for (int g = 1; g < KG; ++g) v += red[g * CT + cl][r];
            v += b[col];
            if (RELU) v = fmaxf(v, 0.f);
            C[(size_t)(row0 + r) * N + col] = v;
        }
    }
}

// ---- fused final head: z[row] = relu(A[row]@W1+b1) . w2 + b2 --------------
__global__ __launch_bounds__(256) void head_kernel(
        const float* __restrict__ A, const float* __restrict__ W1,
        const float* __restrict__ b1, const float* __restrict__ w2,
        const float* __restrict__ b2, float* __restrict__ z) {
    __shared__ float As[512];
    __shared__ float red[4];
    int row = blockIdx.x;
    int t = threadIdx.x;
    for (int k = t; k < 512; k += 256) As[k] = A[(size_t)row * 512 + k];
    __syncthreads();
    float acc = 0.f;
    #pragma unroll 8
    for (int k = 0; k < 512; ++k)
        acc += As[k] * W1[(size_t)k * 256 + t];
    float h = fmaxf(acc + b1[t], 0.f);
    float v = h * w2[t];
    #pragma unroll
    for (int o = 32; o > 0; o >>= 1) v += __shfl_down(v, o, 64);
    if ((t & 63) == 0) red[t >> 6] = v;
    __syncthreads();
    if (t == 0) z[row] = red[0] + red[1] + red[2] + red[3] + b2[0];
}

// ---------------------------------------------------------------------------
static inline int cdiv(int a, int b) { return (a + b - 1) / b; }

template<int F, int KP, int FO, int NT, int BD_LIN, int KFC>
static void run_branch(const float* feat, const int* ei, int E, int N,
                       const int* seg,
                       const float* W1, const float* b1,
                       const float* W2, const float* b2,
                       const float* fw1, const float* fb1,
                       const float* fw2, const float* fb2,
                       const float* hw1, const float* hb1,
                       const float* hw2, const float* hb2,
                       float* agg, float* h1, float* p, float* t1,
                       float* ppmax, float* ppsum, short* Wb,
                       int* cnt, int* offs, int* deg, int* rowoff, int* cursor,
                       int* csr, int* bsum,
                       float* xg_out, float* z_out, hipStream_t stream) {
    constexpr int NS = 4;
    // graph segment offsets
    hipMemsetAsync(cnt, 0, NG * sizeof(int), stream);
    hist_kernel<<<cdiv(N, 256), 256, 0, stream>>>(seg, N, cnt);
    seg_scan_kernel<<<1, 64, 0, stream>>>(cnt, offs);

    // CSR build (bucket edges by dst, reused for both GIN layers)
    hipMemsetAsync(deg, 0, N * sizeof(int), stream);
    deg_kernel<<<cdiv(E, 256), 256, 0, stream>>>(ei, E, deg);
    int nb = cdiv(N, 1024);
    scan1_kernel<<<nb, 256, 0, stream>>>(deg, N, rowoff, bsum);
    scan2_kernel<<<1, 64, 0, stream>>>(bsum, nb);
    scan3_kernel<<<cdiv(N, 256), 256, 0, stream>>>(rowoff, bsum, N, E);
    copy_kernel<<<cdiv(N, 256), 256, 0, stream>>>(cursor, rowoff, N);
    fill_csr_kernel<<<cdiv(E, 256), 256, 0, stream>>>(ei, E, cursor, csr);

    // W2 -> bf16 B-fragment layout
    repack_w_kernel<F, KP, FO, NT><<<cdiv(NT * 16, 256), 256, 0, stream>>>(W2, Wb);

    // GIN layer 1
    gather_kernel<F><<<cdiv(N, 4), 256, 0, stream>>>(feat, csr, rowoff, agg, N);
    gin_linear_kernel<F, BD_LIN><<<cdiv(N, 32), BD_LIN, 0, stream>>>(feat, agg, W1, b1, h1, N);

    // GIN layer 2 fused with pooling (MFMA)
    gather_kernel<F><<<cdiv(N, 4), 256, 0, stream>>>(h1, csr, rowoff, agg, N);
    gin_pool_mfma_kernel<F, KP, FO, NT, NS><<<NG * NS, 256, 0, stream>>>(
        h1, agg, Wb, b2, offs, ppmax, ppsum);
    pool_reduce_kernel<FO, NS><<<NG, 256, 0, stream>>>(ppmax, ppsum, offs, p);

    // FC heads (split-K): p[NG,KFC] -> t1[NG,1024] -> xg[NG,512] -> z[NG]
    fc_kernel<KFC,  4, 4, true ><<<(NG / 4) * (1024 / 64), 256, 0, stream>>>(p,  fw1, fb1, t1, 1024);
    fc_kernel<1024, 4, 4, false><<<(NG / 4) * ( 512 / 64), 256, 0, stream>>>(t1, fw2, fb2, xg_out, 512);
    head_kernel<<<NG, 256, 0, stream>>>(xg_out, hw1, hb1, hw2, hb2, z_out);
}

extern "C" void kernel_launch(void* const* d_in, const int* in_sizes, int n_in,
                              void* d_out, int out_size, void* d_ws, size_t ws_size,
                              hipStream_t stream) {
    (void)n_in; (void)out_size; (void)ws_size;
    const float* x      = (const float*)d_in[1];
    const int*   ei     = (const int*)  d_in[2];
    const int*   batch  = (const int*)  d_in[3];
    const float* a      = (const float*)d_in[4];
    const int*   ed     = (const int*)  d_in[5];
    const int*   c      = (const int*)  d_in[6];
    const float* W1  = (const float*)d_in[7],  *b1  = (const float*)d_in[8];
    const float* W2  = (const float*)d_in[9],  *b2  = (const float*)d_in[10];
    const float* W3  = (const float*)d_in[11], *b3  = (const float*)d_in[12];
    const float* W4  = (const float*)d_in[13], *b4  = (const float*)d_in[14];
    const float* fg_w1  = (const float*)d_in[15], *fg_b1  = (const float*)d_in[16];
    const float* fg_w2  = (const float*)d_in[17], *fg_b2  = (const float*)d_in[18];
    const float* fg1_w1 = (const float*)d_in[19], *fg1_b1 = (const float*)d_in[20];
    const float* fg1_w2 = (const float*)d_in[21], *fg1_b2 = (const float*)d_in[22];
    const float* ff_w1  = (const float*)d_in[23], *ff_b1  = (const float*)d_in[24];
    const float* ff_w2  = (const float*)d_in[25], *ff_b2  = (const float*)d_in[26];
    const float* ff1_w1 = (const float*)d_in[27], *ff1_b1 = (const float*)d_in[28];
    const float* ff1_w2 = (const float*)d_in[29], *ff1_b2 = (const float*)d_in[30];

    const int N1 = in_sizes[1] / 93;
    const int E1 = in_sizes[2] / 2;
    const int N2 = in_sizes[4] / 43;
    const int E2 = in_sizes[5] / 2;

    float* out = (float*)d_out;
    float* z   = out;                       // [256]
    float* xg  = out + 256;                 // [256,512]
    float* xg1 = out + 256 + 256 * 512;     // [256,512]
    float* z1  = out + 256 + 2 * 256 * 512; // [256]

    char* wsb = (char*)d_ws;
    size_t off = 0;
    auto carve = [&](size_t bytes) {
        void* ptr = wsb + off;
        off = (off + bytes + 255) & ~(size_t)255;
        return ptr;
    };
    float* agg = (float*)carve((size_t)N1 * 93 * sizeof(float));
    float* h1  = (float*)carve((size_t)N1 * 93 * sizeof(float));
    float* p   = (float*)carve((size_t)NG * 1860 * sizeof(float));
    float* t1  = (float*)carve((size_t)NG * 1024 * sizeof(float));
    float* ppmax = (float*)carve((size_t)NG * 4 * 930 * sizeof(float));
    float* ppsum = (float*)carve((size_t)NG * 4 * 930 * sizeof(float));
    short* Wb    = (short*)carve((size_t)59 * 16 * 96 * sizeof(short));
    int*   cnt    = (int*)carve(NG * sizeof(int));
    int*   offs   = (int*)carve((NG + 1) * sizeof(int));
    int*   deg    = (int*)carve((size_t)N1 * sizeof(int));
    int*   rowoff = (int*)carve((size_t)(N1 + 1) * sizeof(int));
    int*   cursor = (int*)carve((size_t)N1 * sizeof(int));
    int*   csr    = (int*)carve((size_t)E1 * sizeof(int));
    int*   bsum   = (int*)carve(128 * sizeof(int));

    // branch 1: 93 -> 93 -> 930, pool 1860   (KP=96, NT=59)
    run_branch<93, 96, 930, 59, 128, 1860>(x, ei, E1, N1, batch,
                                W1, b1, W2, b2,
                                fg_w1, fg_b1, fg_w2, fg_b2,
                                ff_w1, ff_b1, ff_w2, ff_b2,
                                agg, h1, p, t1, ppmax, ppsum, Wb,
                                cnt, offs, deg, rowoff, cursor, csr, bsum,
                                xg, z, stream);

    // branch 2: 43 -> 43 -> 430, pool 860    (KP=64, NT=27; reuses scratch)
    run_branch<43, 64, 430, 27, 64, 860>(a, ed, E2, N2, c,
                               W3, b3, W4, b4,
                               fg1_w1, fg1_b1, fg1_w2, fg1_b2,
                               ff1_w1, ff1_b1, ff1_w2, ff1_b2,
                               agg, h1, p, t1, ppmax, ppsum, Wb,
                               cnt, offs, deg, rowoff, cursor, csr, bsum,
                               xg1, z1, stream);
}